// Round 2
// baseline (293.177 us; speedup 1.0000x reference)
//
#include <hip/hip_runtime.h>

// AirFitMultiHeadDNN: per item b:
//   ev[h]   = emb[e[b,h]]                        (3)
//   fv[h]   = f[b,h,:] @ Wf + bf                 (5)
//   x[h]    = [ev, fv]                           (8)
//   h1[h]   = leaky_relu(x @ W1[h] + b1[h])      (10)
//   s[h]    = softplus(h1 . W2[h] + b2[h])
//   out[b]  = sum_h s[h]*Wo[h] + bo
//
// R2: round 1 showed the compiler demoted the 88-element preloaded input
// arrays (VGPR_Count=32!) and re-materialized global loads per use ->
// 2x FETCH_SIZE + 3x VALU inflation. Fix: process heads in 5 groups of 4,
// loading one int4 + three float4 per group (peak live payload ~16 regs),
// and give the allocator a 128-VGPR budget via __launch_bounds__(256,4)
// so hoisted loads stay in registers. Weights stay wave-uniform ->
// s_load/SGPR (SGPR_Count=112 in R1 confirms). Embedding gather via LDS,
// rows padded to 4 floats (2-way bank aliasing is free on gfx950).

#define HH   20
#define NEX  13

__global__ __launch_bounds__(256, 4) void airfit_kernel(
    const int*   __restrict__ e,   const float* __restrict__ f,
    const float* __restrict__ emb, const float* __restrict__ Wf,
    const float* __restrict__ bf,  const float* __restrict__ W1,
    const float* __restrict__ b1,  const float* __restrict__ W2,
    const float* __restrict__ b2,  const float* __restrict__ Wo,
    const float* __restrict__ bo,  float* __restrict__ out, int B)
{
    __shared__ float s_emb[NEX * 4];   // rows padded to 4 floats
    if (threadIdx.x < NEX * 3) {
        int r = threadIdx.x / 3;
        int c = threadIdx.x - r * 3;
        s_emb[r * 4 + c] = emb[threadIdx.x];
    }
    __syncthreads();

    int b = blockIdx.x * 256 + threadIdx.x;
    if (b >= B) return;

    const int4*   ep = reinterpret_cast<const int4*>(e + (size_t)b * HH);
    const float4* fp = reinterpret_cast<const float4*>(f + (size_t)b * (HH * 3));

    float acc = bo[0];

#pragma unroll
    for (int g = 0; g < 5; ++g) {
        // one group's inputs: 4 head indices + 12 feature floats (all 16B-aligned)
        int4   iv = ep[g];
        float4 fa = fp[3 * g + 0];
        float4 fb = fp[3 * g + 1];
        float4 fc = fp[3 * g + 2];
        int   ii[4]  = { iv.x, iv.y, iv.z, iv.w };
        float ff[12] = { fa.x, fa.y, fa.z, fa.w,
                         fb.x, fb.y, fb.z, fb.w,
                         fc.x, fc.y, fc.z, fc.w };

#pragma unroll
        for (int j = 0; j < 4; ++j) {
            const int h = 4 * g + j;        // compile-time constant after unroll
            int idx = ii[j];

            float xv[8];
            xv[0] = s_emb[idx * 4 + 0];
            xv[1] = s_emb[idx * 4 + 1];
            xv[2] = s_emb[idx * 4 + 2];

            // features Linear 3->5 (Wf stored (in,out))
            float g0 = ff[3 * j + 0], g1 = ff[3 * j + 1], g2 = ff[3 * j + 2];
#pragma unroll
            for (int o = 0; o < 5; ++o) {
                float a = bf[o];
                a = fmaf(g0, Wf[0 * 5 + o], a);
                a = fmaf(g1, Wf[1 * 5 + o], a);
                a = fmaf(g2, Wf[2 * 5 + o], a);
                xv[3 + o] = a;
            }

            // head MLP 8->10, leaky_relu, dot with W2 -> scalar
            float hacc = b2[h];
#pragma unroll
            for (int o = 0; o < 10; ++o) {
                float a = b1[h * 10 + o];
#pragma unroll
                for (int i = 0; i < 8; ++i)
                    a = fmaf(xv[i], W1[(h * 8 + i) * 10 + o], a);
                a = fmaxf(a, 0.01f * a);               // leaky_relu, slope .01
                hacc = fmaf(a, W2[h * 10 + o], hacc);
            }

            // softplus = logaddexp(x, 0) = max(x,0) + log1p(exp(-|x|))
            float sp = fmaxf(hacc, 0.0f) + __logf(1.0f + __expf(-fabsf(hacc)));
            acc = fmaf(sp, Wo[h], acc);
        }
    }

    out[b] = acc;
}

extern "C" void kernel_launch(void* const* d_in, const int* in_sizes, int n_in,
                              void* d_out, int out_size, void* d_ws, size_t ws_size,
                              hipStream_t stream) {
    const int*   e   = (const int*)  d_in[0];
    const float* f   = (const float*)d_in[1];
    const float* emb = (const float*)d_in[2];
    const float* Wf  = (const float*)d_in[3];
    const float* bf  = (const float*)d_in[4];
    const float* W1  = (const float*)d_in[5];
    const float* b1  = (const float*)d_in[6];
    const float* W2  = (const float*)d_in[7];
    const float* b2  = (const float*)d_in[8];
    const float* Wo  = (const float*)d_in[9];
    const float* bo  = (const float*)d_in[10];
    float* out = (float*)d_out;

    int B = in_sizes[0] / HH;          // e is (B, 20)
    int blocks = (B + 255) / 256;
    airfit_kernel<<<blocks, 256, 0, stream>>>(e, f, emb, Wf, bf, W1, b1,
                                              W2, b2, Wo, bo, out, B);
}